// Round 2
// baseline (723.030 us; speedup 1.0000x reference)
//
#include <hip/hip_runtime.h>
#include <hip/hip_bf16.h>
#include <math.h>

constexpr int B_ = 16, C_ = 96, O_ = 48, R_ = 4, H_ = 66, W_ = 66;
constexpr int HW_ = H_ * W_;            // 4356
constexpr int HO_ = 64, WO_ = 64;       // valid-conv output spatial
constexpr int OC_ = O_ + C_;            // 144 output channels
constexpr float EPS_ = 2e-5f;
constexpr int KP_ = 32;                 // planes per K-chunk
constexpr int NCH_ = (C_*R_)/KP_;       // 12 chunks
constexpr int NPG_ = (C_*R_)/8;         // 48 plane-groups (8 planes each)
constexpr int ROWS_ = 16;               // out-rows per block
constexpr int SR_ = ROWS_ + 2;          // staged input rows (halo)
constexpr int GPC_ = SR_*W_;            // 1188 positions per quad-plane-group
constexpr int WIMG_ = 9*3*64*8;         // 13824 bf16 per (h,chunk) weight image
constexpr int STRIPE_ = HW_/4;          // 1089 positions per fstats block

// workspace layout (float offsets)
constexpr int WS_SUM   = 0;
constexpr int WS_SUMSQ = WS_SUM + C_;
constexpr int WS_SCALE = WS_SUMSQ + C_;
constexpr int WS_SHIFT = WS_SCALE + C_;
constexpr int WS_SAVG  = WS_SHIFT + C_;                    // [B][C][R] raw sums
constexpr int WS_SMAX  = WS_SAVG + B_*C_*R_;               // [B][C][R] max as int bits
constexpr int WS_CHATT = WS_SMAX + B_*C_*R_;               // [B][h][C][r]
constexpr int WS_UMEAN = WS_CHATT + B_*R_*C_*R_;           // [B][r][HW]
constexpr int WS_UMAX  = WS_UMEAN + B_*R_*HW_;
constexpr int WS_SPATT = WS_UMAX + B_*R_*HW_;              // [B][h][HW]
constexpr int WS_WROT  = WS_SPATT + B_*R_*HW_;             // bf16 [h][chunk][tap][nt][lane][8]
constexpr int WS_Z     = WS_WROT + (R_*NCH_*WIMG_)/2;      // bf16 z[b][h][pg][pos][8]
constexpr long long Z_BF16 = (long long)B_*R_*NPG_*HW_*8;  // 107,053,056 elements
constexpr unsigned long long WS_NEED_BYTES =
    (unsigned long long)WS_Z*4ull + (unsigned long long)Z_BF16*2ull; // ~219 MB

typedef __attribute__((ext_vector_type(8))) __bf16 bf16x8;
typedef __attribute__((ext_vector_type(4))) float f32x4;

__device__ __forceinline__ float sigm(float v){ return 1.0f/(1.0f + __expf(-v)); }

// async global->LDS, 16B per lane; LDS dest must be linear (base + lane*16)
__device__ __forceinline__ void gl_lds16(const void* g, void* l) {
  __builtin_amdgcn_global_load_lds(
      (const __attribute__((address_space(1))) unsigned int*)g,
      (__attribute__((address_space(3))) unsigned int*)l, 16, 0, 0);
}

// ---- K1: BN batch statistics ----
__global__ void k_bn_stats(const float* __restrict__ x, float* __restrict__ ws) {
  int b = blockIdx.x, c = blockIdx.y;
  const float4* p = (const float4*)(x + (size_t)(b*C_ + c) * (R_*HW_));
  int tid = threadIdx.x;
  float s = 0.f, ss = 0.f;
  for (int i = tid; i < R_*HW_/4; i += 256) {
    float4 v = p[i];
    s += v.x + v.y + v.z + v.w;
    ss += v.x*v.x + v.y*v.y + v.z*v.z + v.w*v.w;
  }
  __shared__ float rs[256], rq[256];
  rs[tid] = s; rq[tid] = ss; __syncthreads();
  for (int off = 128; off > 0; off >>= 1) {
    if (tid < off) { rs[tid] += rs[tid+off]; rq[tid] += rq[tid+off]; }
    __syncthreads();
  }
  if (tid == 0) {
    atomicAdd(&ws[WS_SUM + c], rs[0]);
    atomicAdd(&ws[WS_SUMSQ + c], rq[0]);
  }
}

// ---- K2: finalize scale/shift ----
__global__ void k_bn_finalize(const float* __restrict__ gamma, const float* __restrict__ beta,
                              float* __restrict__ ws) {
  int c = threadIdx.x;
  if (c < C_) {
    float n = (float)(B_ * R_ * HW_);
    float mu = ws[WS_SUM + c] / n;
    float var = ws[WS_SUMSQ + c] / n - mu*mu;
    float sc = gamma[c] * rsqrtf(var + EPS_);
    ws[WS_SCALE + c] = sc;
    ws[WS_SHIFT + c] = beta[c] - mu * sc;
  }
}

// ---- K3 (fused): single x pass per (b,r,stripe) producing
//   * per-(b,c,r) spatial sum / max of y   (wave partials -> atomics)
//   * per-(b,r,pos) channel mean / max of y (umean/umax)
//   * crop-copy of raw x into out tail
__global__ void k_fstats(const float* __restrict__ x, float* __restrict__ ws,
                         float* __restrict__ out) {
  int stripe = blockIdx.x, r = blockIdx.y, b = blockIdx.z;
  int tid = threadIdx.x;
  int lane = tid & 63;
  int pos0 = stripe * STRIPE_;

  float ps[5], pm[5];
  #pragma unroll
  for (int k = 0; k < 5; ++k) { ps[k] = 0.f; pm[k] = 0.f; }
  int row[5], col[5]; bool inc[5];
  #pragma unroll
  for (int k = 0; k < 5; ++k) {
    int e = tid + k*256;
    int pos = pos0 + e;
    int rw = pos / W_, cl = pos - rw*W_;
    row[k] = rw; col[k] = cl;
    inc[k] = (e < STRIPE_) && rw >= 1 && rw <= 64 && cl >= 1 && cl <= 64;
  }

  for (int c = 0; c < C_; ++c) {
    float sc = ws[WS_SCALE + c], sh = ws[WS_SHIFT + c];
    const float* xp = x + (size_t)((b*C_ + c)*R_ + r)*HW_ + pos0;
    float* op = out + ((size_t)(b*OC_ + O_ + c)*R_ + r)*(size_t)(HO_*WO_);
    float cs = 0.f, cm = 0.f;
    #pragma unroll
    for (int k = 0; k < 5; ++k) {
      int e = tid + k*256;
      if (e < STRIPE_) {
        float xv = xp[e];
        float yv = fmaxf(fmaf(xv, sc, sh), 0.f);
        ps[k] += yv; pm[k] = fmaxf(pm[k], yv);
        cs += yv;    cm = fmaxf(cm, yv);
        if (inc[k]) op[(row[k]-1)*WO_ + (col[k]-1)] = xv;
      }
    }
    #pragma unroll
    for (int off = 32; off > 0; off >>= 1) {
      cs += __shfl_down(cs, off);
      cm = fmaxf(cm, __shfl_down(cm, off));
    }
    if (lane == 0) {
      int idx = (b*C_ + c)*R_ + r;
      atomicAdd(&ws[WS_SAVG + idx], cs);
      atomicMax((int*)ws + WS_SMAX + idx, __float_as_int(cm));  // y>=0: int max == float max
    }
  }
  #pragma unroll
  for (int k = 0; k < 5; ++k) {
    int e = tid + k*256;
    if (e < STRIPE_) {
      int idx = (b*R_ + r)*HW_ + pos0 + e;
      ws[WS_UMEAN + idx] = ps[k] * (1.0f/(float)C_);
      ws[WS_UMAX + idx]  = pm[k];
    }
  }
}

// ---- K5: channel attention MLP ----
__global__ void k_chatt(const float* __restrict__ fc1, const float* __restrict__ fc2,
                        float* __restrict__ ws) {
  int b = blockIdx.x, tid = threadIdx.x;
  __shared__ float sA[C_*R_], sM[C_*R_], hs[8];
  for (int i = tid; i < C_*R_; i += 256) {
    sA[i] = ws[WS_SAVG + b*C_*R_ + i] * (1.0f/(float)HW_);      // raw sum -> mean
    sM[i] = __int_as_float(((const int*)ws)[WS_SMAX + b*C_*R_ + i]);
  }
  __syncthreads();
  if (tid < 8) {
    int h = tid >> 1, e = tid & 1;
    float aA = 0.f, aM = 0.f;
    for (int c = 0; c < C_; ++c)
      for (int r = 0; r < R_; ++r) {
        float w = fc1[(e*C_ + c)*R_ + ((r - h) & 3)];
        aA += sA[c*R_ + r] * w;
        aM += sM[c*R_ + r] * w;
      }
    hs[tid] = fmaxf(aA, 0.f) + fmaxf(aM, 0.f);
  }
  __syncthreads();
  for (int idx = tid; idx < R_*C_*R_; idx += 256) {
    int h = idx / (C_*R_);
    int c = (idx % (C_*R_)) / R_;
    int r = idx & 3;
    int rr = (r - h) & 3;
    float v = hs[h*2+0] * fc2[(c*2+0)*R_ + rr]
            + hs[h*2+1] * fc2[(c*2+1)*R_ + rr];
    ws[WS_CHATT + b*R_*C_*R_ + idx] = sigm(v);
  }
}

// ---- K6: spatial attention 7x7 group conv ----
__global__ void k_spatt(const float* __restrict__ saw, float* __restrict__ ws) {
  int h = blockIdx.y, b = blockIdx.z;
  int tid = threadIdx.x;
  __shared__ float wl[2*R_*49];
  for (int e = tid; e < 2*R_*49; e += 256) {
    int g = e / (R_*49);
    int s = (e / 49) % R_;
    int ij = e % 49;
    int i = ij / 7, j = ij % 7;
    int si, sj;
    if (h == 0)      { si = i;     sj = j;     }
    else if (h == 1) { si = j;     sj = 6 - i; }
    else if (h == 2) { si = 6 - i; sj = 6 - j; }
    else             { si = 6 - j; sj = i;     }
    int srot = (s - h) & 3;
    wl[e] = saw[(g*R_ + srot)*49 + si*7 + sj];
  }
  __syncthreads();
  int pos = blockIdx.x*256 + tid;
  if (pos >= HW_) return;
  int y = pos / W_, xx = pos % W_;
  float acc = 0.f;
  for (int g = 0; g < 2; ++g) {
    const float* u = ws + (g ? WS_UMAX : WS_UMEAN) + (size_t)b*R_*HW_;
    for (int s = 0; s < R_; ++s) {
      const float* up = u + s*HW_;
      const float* wp = wl + (g*R_ + s)*49;
      for (int i = 0; i < 7; ++i) {
        int yy = y + i - 3;
        if (yy < 0 || yy >= H_) continue;
        for (int j = 0; j < 7; ++j) {
          int xc = xx + j - 3;
          if (xc < 0 || xc >= W_) continue;
          acc += up[yy*W_ + xc] * wp[i*7 + j];
        }
      }
    }
  }
  ws[WS_SPATT + (b*R_ + h)*HW_ + pos] = sigm(acc);
}

// ---- K7: pre-rotate conv weights into lane-ordered MFMA fragment images ----
__global__ void k_wrot(const float* __restrict__ cw, float* __restrict__ ws) {
  int chunk = blockIdx.x, h = blockIdx.y;
  __bf16* wp = (__bf16*)(ws + WS_WROT) + (size_t)(h*NCH_ + chunk)*WIMG_;
  for (int e = threadIdx.x; e < WIMG_; e += 256) {
    int kk = e & 7;
    int lane = (e >> 3) & 63;
    int nt = (e >> 9) % 3;
    int tap = e / (3*512);
    int o = nt*16 + (lane & 15);
    int plane = chunk*KP_ + (lane >> 4)*8 + kk;
    int c = plane >> 2, r = plane & 3;
    int rr = (r - h) & 3;
    int i = tap / 3, j = tap % 3;
    int si, sj;
    if (h == 0)      { si = i;     sj = j;     }
    else if (h == 1) { si = j;     sj = 2 - i; }
    else if (h == 2) { si = 2 - i; sj = 2 - j; }
    else             { si = 2 - j; sj = i;     }
    wp[e] = (__bf16)cw[((size_t)(o*C_ + c)*R_ + rr)*9 + si*3 + sj];
  }
}

// ---- K7b: z-pack producer — z[b][h][pg][pos][8] = relu(BN(x)) * ch_att * sp_att ----
// Written in the exact LDS fragment layout so k_conv2 staging is pure DMA.
__global__ void k_zpack(const float* __restrict__ x, float* __restrict__ ws) {
  int pg = blockIdx.y, b = blockIdx.z;
  int pos = blockIdx.x*256 + threadIdx.x;
  if (pos >= HW_) return;
  int c0 = pg*2;
  float sc0 = ws[WS_SCALE+c0],   sh0 = ws[WS_SHIFT+c0];
  float sc1 = ws[WS_SCALE+c0+1], sh1 = ws[WS_SHIFT+c0+1];
  const float* xp = x + (size_t)(b*C_ + c0)*R_*HW_ + pos;
  float yv[8];
  #pragma unroll
  for (int kk = 0; kk < 8; ++kk)
    yv[kk] = fmaxf(fmaf(xp[(size_t)kk*HW_], (kk < 4 ? sc0 : sc1),
                        (kk < 4 ? sh0 : sh1)), 0.f);
  __bf16* zp = (__bf16*)(ws + WS_Z);
  #pragma unroll
  for (int h = 0; h < R_; ++h) {
    float sa = ws[WS_SPATT + (size_t)(b*R_ + h)*HW_ + pos];
    const float* ca = ws + WS_CHATT + (size_t)(b*R_ + h)*C_*R_ + pg*8;
    bf16x8 pk;
    #pragma unroll
    for (int kk = 0; kk < 8; ++kk)
      pk[kk] = (__bf16)(yv[kk] * ca[kk] * sa);
    *(bf16x8*)&zp[(((size_t)(b*R_ + h)*NPG_ + pg)*HW_ + pos)*8] = pk;
  }
}

// ---- K8 (fallback path): main conv via MFMA implicit GEMM, fused transform ----
__global__ __launch_bounds__(512, 2) void k_conv(
    const float* __restrict__ x, const float* __restrict__ ws,
    float* __restrict__ out) {
  int ytile = blockIdx.x, h = blockIdx.y, b = blockIdx.z;
  int y0 = ytile * ROWS_;
  int tid = threadIdx.x;
  int lane = tid & 63, wave = tid >> 6;
  int m = lane & 15, quad = lane >> 4;
  int colgrp = wave & 1, rowgrp = wave >> 1;
  int dy0 = rowgrp * 4, colbase = colgrp * 32;

  __shared__ __align__(16) __bf16 zl[4*GPC_*8];
  __shared__ __align__(16) __bf16 wl[WIMG_];
  __shared__ float satt_l[GPC_];
  __shared__ float catt_l[C_*R_];
  __shared__ float scl[C_], shl[C_];

  const float* sp = ws + WS_SPATT + (size_t)(b*R_ + h)*HW_;
  for (int e = tid; e < GPC_; e += 512) satt_l[e] = sp[(y0 + e/W_)*W_ + e%W_];
  const float* chatt = ws + WS_CHATT + (size_t)(b*R_ + h)*C_*R_;
  for (int e = tid; e < C_*R_; e += 512) catt_l[e] = chatt[e];
  for (int e = tid; e < C_; e += 512) { scl[e] = ws[WS_SCALE+e]; shl[e] = ws[WS_SHIFT+e]; }

  f32x4 acc[4][2][3];
  #pragma unroll
  for (int dy = 0; dy < 4; ++dy)
    #pragma unroll
    for (int gi = 0; gi < 2; ++gi)
      #pragma unroll
      for (int nt = 0; nt < 3; ++nt) acc[dy][gi][nt] = (f32x4){0.f,0.f,0.f,0.f};

  const __bf16* wglob = (const __bf16*)(ws + WS_WROT) + (size_t)h*NCH_*WIMG_;
  int sq = tid & 3, sg0 = tid >> 2;
  __syncthreads();

  for (int chunk = 0; chunk < NCH_; ++chunk) {
    int pbase = chunk*KP_ + sq*8;
    int cb = pbase >> 2;
    float sc0 = scl[cb], sh0 = shl[cb], sc1 = scl[cb+1], sh1 = shl[cb+1];
    float ca[8];
    #pragma unroll
    for (int kk = 0; kk < 8; ++kk) ca[kk] = catt_l[pbase + kk];

    for (int g = sg0; g < GPC_; g += 128) {
      int row = g / W_, col = g - row*W_;
      const float* xp = x + (size_t)(b*C_*R_ + pbase)*HW_ + (y0+row)*W_ + col;
      float sa = satt_l[g];
      bf16x8 pk;
      #pragma unroll
      for (int kk = 0; kk < 8; ++kk) {
        float yv = fmaxf(fmaf(xp[kk*HW_], (kk < 4 ? sc0 : sc1),
                              (kk < 4 ? sh0 : sh1)), 0.f);
        pk[kk] = (__bf16)(yv * ca[kk] * sa);
      }
      *(bf16x8*)&zl[(sq*GPC_ + g)*8] = pk;
    }
    {
      const uint4* wsrc = (const uint4*)(wglob + (size_t)chunk*WIMG_);
      uint4* wdst = (uint4*)wl;
      for (int e = tid; e < WIMG_/8; e += 512) wdst[e] = wsrc[e];
    }
    __syncthreads();
    #pragma unroll
    for (int j = 0; j < 3; ++j) {
      bf16x8 zf[6][2];
      #pragma unroll
      for (int rr = 0; rr < 6; ++rr)
        #pragma unroll
        for (int gi = 0; gi < 2; ++gi)
          zf[rr][gi] = *(const bf16x8*)
              &zl[(quad*GPC_ + (dy0+rr)*W_ + colbase + gi*16 + m + j)*8];
      #pragma unroll
      for (int i = 0; i < 3; ++i) {
        int tap = i*3 + j;
        bf16x8 wf[3];
        #pragma unroll
        for (int nt = 0; nt < 3; ++nt)
          wf[nt] = *(const bf16x8*)&wl[((tap*3 + nt)*64 + lane)*8];
        #pragma unroll
        for (int dy = 0; dy < 4; ++dy)
          #pragma unroll
          for (int gi = 0; gi < 2; ++gi)
            #pragma unroll
            for (int nt = 0; nt < 3; ++nt)
              acc[dy][gi][nt] = __builtin_amdgcn_mfma_f32_16x16x32_bf16(
                  wf[nt], zf[dy+i][gi], acc[dy][gi][nt], 0, 0, 0);
      }
    }
    __syncthreads();
  }
  #pragma unroll
  for (int dy = 0; dy < 4; ++dy)
    #pragma unroll
    for (int gi = 0; gi < 2; ++gi)
      #pragma unroll
      for (int nt = 0; nt < 3; ++nt) {
        int col = colbase + gi*16 + m;
        #pragma unroll
        for (int e = 0; e < 4; ++e) {
          int o = nt*16 + quad*4 + e;
          out[((size_t)(b*OC_ + o)*R_ + h)*((size_t)HO_*WO_)
              + (y0 + dy0 + dy)*WO_ + col] = acc[dy][gi][nt][e];
        }
      }
}

// ---- K8b: main conv, staging = pure async DMA from pre-packed z + weights ----
__global__ __launch_bounds__(512, 2) void k_conv2(
    const float* __restrict__ ws, float* __restrict__ out) {
  int ytile = blockIdx.x, h = blockIdx.y, b = blockIdx.z;
  int y0 = ytile * ROWS_;
  int tid = threadIdx.x;
  int lane = tid & 63, wave = tid >> 6;
  int m = lane & 15, quad = lane >> 4;
  int colgrp = wave & 1, rowgrp = wave >> 1;
  int dy0 = rowgrp * 4, colbase = colgrp * 32;

  __shared__ __align__(16) __bf16 zl[4*GPC_*8];   // 76032 B
  __shared__ __align__(16) __bf16 wl[WIMG_];      // 27648 B

  f32x4 acc[4][2][3];
  #pragma unroll
  for (int dy = 0; dy < 4; ++dy)
    #pragma unroll
    for (int gi = 0; gi < 2; ++gi)
      #pragma unroll
      for (int nt = 0; nt < 3; ++nt) acc[dy][gi][nt] = (f32x4){0.f,0.f,0.f,0.f};

  const __bf16* wglob = (const __bf16*)(ws + WS_WROT) + (size_t)h*NCH_*WIMG_;
  const __bf16* zglob = (const __bf16*)(ws + WS_Z)
      + (size_t)(b*R_ + h)*NPG_*HW_*8 + (size_t)y0*W_*8;

  for (int chunk = 0; chunk < NCH_; ++chunk) {
    const __bf16* zb = zglob + (size_t)(chunk*4)*HW_*8;
    for (int e = tid; e < 4*GPC_; e += 512) {
      int sq = e / GPC_, off = e - sq*GPC_;
      gl_lds16(zb + ((size_t)sq*HW_ + off)*8, &zl[e*8]);
    }
    const __bf16* wsrc = wglob + (size_t)chunk*WIMG_;
    for (int e = tid; e < WIMG_/8; e += 512)
      gl_lds16(wsrc + (size_t)e*8, &wl[e*8]);
    __syncthreads();   // drains vmcnt(0): all DMA landed
    #pragma unroll
    for (int j = 0; j < 3; ++j) {
      bf16x8 zf[6][2];
      #pragma unroll
      for (int rr = 0; rr < 6; ++rr)
        #pragma unroll
        for (int gi = 0; gi < 2; ++gi)
          zf[rr][gi] = *(const bf16x8*)
              &zl[(quad*GPC_ + (dy0+rr)*W_ + colbase + gi*16 + m + j)*8];
      #pragma unroll
      for (int i = 0; i < 3; ++i) {
        int tap = i*3 + j;
        bf16x8 wf[3];
        #pragma unroll
        for (int nt = 0; nt < 3; ++nt)
          wf[nt] = *(const bf16x8*)&wl[((tap*3 + nt)*64 + lane)*8];
        #pragma unroll
        for (int dy = 0; dy < 4; ++dy)
          #pragma unroll
          for (int gi = 0; gi < 2; ++gi)
            #pragma unroll
            for (int nt = 0; nt < 3; ++nt)
              acc[dy][gi][nt] = __builtin_amdgcn_mfma_f32_16x16x32_bf16(
                  wf[nt], zf[dy+i][gi], acc[dy][gi][nt], 0, 0, 0);
      }
    }
    __syncthreads();   // all reads done before next chunk's DMA overwrites
  }
  #pragma unroll
  for (int dy = 0; dy < 4; ++dy)
    #pragma unroll
    for (int gi = 0; gi < 2; ++gi)
      #pragma unroll
      for (int nt = 0; nt < 3; ++nt) {
        int col = colbase + gi*16 + m;
        #pragma unroll
        for (int e = 0; e < 4; ++e) {
          int o = nt*16 + quad*4 + e;
          out[((size_t)(b*OC_ + o)*R_ + h)*((size_t)HO_*WO_)
              + (y0 + dy0 + dy)*WO_ + col] = acc[dy][gi][nt][e];
        }
      }
}

extern "C" void kernel_launch(void* const* d_in, const int* in_sizes, int n_in,
                              void* d_out, int out_size, void* d_ws, size_t ws_size,
                              hipStream_t stream) {
  const float* x     = (const float*)d_in[0];
  const float* gamma = (const float*)d_in[1];
  const float* beta  = (const float*)d_in[2];
  const float* fc1   = (const float*)d_in[3];
  const float* fc2   = (const float*)d_in[4];
  const float* saw   = (const float*)d_in[5];
  const float* cw    = (const float*)d_in[6];
  float* out = (float*)d_out;
  float* ws = (float*)d_ws;

  // zero BN accumulators + savg/smax atomic targets (scale/shift overwritten later)
  hipMemsetAsync(d_ws, 0, WS_CHATT * sizeof(float), stream);
  k_bn_stats   <<<dim3(B_, C_),                256, 0, stream>>>(x, ws);
  k_bn_finalize<<<1, 128,                           0, stream>>>(gamma, beta, ws);
  k_wrot       <<<dim3(NCH_, R_),              256, 0, stream>>>(cw, ws);
  k_fstats     <<<dim3(4, R_, B_),             256, 0, stream>>>(x, ws, out);
  k_chatt      <<<B_, 256,                          0, stream>>>(fc1, fc2, ws);
  k_spatt      <<<dim3((HW_+255)/256, R_, B_), 256, 0, stream>>>(saw, ws);

  if ((unsigned long long)ws_size >= WS_NEED_BYTES) {
    // fast path: pre-pack attention-gated z, then pure-DMA MFMA conv
    k_zpack<<<dim3((HW_+255)/256, NPG_, B_),   256, 0, stream>>>(x, ws);
    k_conv2<<<dim3(HO_/ROWS_, R_, B_),         512, 0, stream>>>(ws, out);
  } else {
    // fallback: verified fused-transform conv (workspace too small for z)
    k_conv <<<dim3(HO_/ROWS_, R_, B_),         512, 0, stream>>>(x, ws, out);
  }
}

// Round 4
// 523.773 us; speedup vs baseline: 1.3804x; 1.3804x over previous
//
#include <hip/hip_runtime.h>
#include <hip/hip_bf16.h>
#include <math.h>

constexpr int B_ = 16, C_ = 96, O_ = 48, R_ = 4, H_ = 66, W_ = 66;
constexpr int HW_ = H_ * W_;            // 4356
constexpr int HO_ = 64, WO_ = 64;       // valid-conv output spatial
constexpr int OC_ = O_ + C_;            // 144 output channels
constexpr float EPS_ = 2e-5f;
constexpr int KP_ = 32;                 // planes per K-chunk
constexpr int NCH_ = (C_*R_)/KP_;       // 12 chunks
constexpr int NPG_ = (C_*R_)/8;         // 48 plane-groups (8 planes each)
constexpr int ROWS_ = 16;               // out-rows per block (fallback k_conv)
constexpr int SR_ = ROWS_ + 2;          // staged input rows (halo)
constexpr int GPC_ = SR_*W_;            // 1188 positions per quad-plane-group
constexpr int ROWS2_ = 8;               // out-rows per block (k_conv2: 2 blocks/CU)
constexpr int SR2_ = ROWS2_ + 2;        // 10
constexpr int GPC2_ = SR2_*W_;          // 660
constexpr int WIMG_ = 9*3*64*8;         // 13824 bf16 per (h,chunk) weight image

// workspace layout (float offsets)
constexpr int WS_SUM   = 0;
constexpr int WS_SUMSQ = WS_SUM + C_;
constexpr int WS_SCALE = WS_SUMSQ + C_;
constexpr int WS_SHIFT = WS_SCALE + C_;
constexpr int WS_SAVG  = WS_SHIFT + C_;                    // [B][C][R]
constexpr int WS_SMAX  = WS_SAVG + B_*C_*R_;
constexpr int WS_CHATT = WS_SMAX + B_*C_*R_;               // [B][h][C][r]
constexpr int WS_UMEAN = WS_CHATT + B_*R_*C_*R_;           // [B][r][HW]
constexpr int WS_UMAX  = WS_UMEAN + B_*R_*HW_;
constexpr int WS_SPATT = WS_UMAX + B_*R_*HW_;              // [B][h][HW]
constexpr int WS_WROT  = WS_SPATT + B_*R_*HW_;             // bf16 [h][chunk][tap][nt][lane][8]
constexpr int WS_Z     = WS_WROT + (R_*NCH_*WIMG_)/2;      // bf16 z[b][h][pg][pos][8]
constexpr long long Z_BF16 = (long long)B_*R_*NPG_*HW_*8;  // 107,053,056 elements
constexpr unsigned long long WS_NEED_BYTES =
    (unsigned long long)WS_Z*4ull + (unsigned long long)Z_BF16*2ull; // ~219 MB

typedef __attribute__((ext_vector_type(8))) __bf16 bf16x8;
typedef __attribute__((ext_vector_type(4))) float f32x4;

__device__ __forceinline__ float sigm(float v){ return 1.0f/(1.0f + __expf(-v)); }

// async global->LDS, 16B per lane; LDS dest must be linear (base + lane*16)
__device__ __forceinline__ void gl_lds16(const void* g, void* l) {
  __builtin_amdgcn_global_load_lds(
      (const __attribute__((address_space(1))) unsigned int*)g,
      (__attribute__((address_space(3))) unsigned int*)l, 16, 0, 0);
}

// ---- K1: BN batch statistics ----
__global__ void k_bn_stats(const float* __restrict__ x, float* __restrict__ ws) {
  int b = blockIdx.x, c = blockIdx.y;
  const float4* p = (const float4*)(x + (size_t)(b*C_ + c) * (R_*HW_));
  int tid = threadIdx.x;
  float s = 0.f, ss = 0.f;
  for (int i = tid; i < R_*HW_/4; i += 256) {
    float4 v = p[i];
    s += v.x + v.y + v.z + v.w;
    ss += v.x*v.x + v.y*v.y + v.z*v.z + v.w*v.w;
  }
  __shared__ float rs[256], rq[256];
  rs[tid] = s; rq[tid] = ss; __syncthreads();
  for (int off = 128; off > 0; off >>= 1) {
    if (tid < off) { rs[tid] += rs[tid+off]; rq[tid] += rq[tid+off]; }
    __syncthreads();
  }
  if (tid == 0) {
    atomicAdd(&ws[WS_SUM + c], rs[0]);
    atomicAdd(&ws[WS_SUMSQ + c], rq[0]);
  }
}

// ---- K2: finalize scale/shift ----
__global__ void k_bn_finalize(const float* __restrict__ gamma, const float* __restrict__ beta,
                              float* __restrict__ ws) {
  int c = threadIdx.x;
  if (c < C_) {
    float n = (float)(B_ * R_ * HW_);
    float mu = ws[WS_SUM + c] / n;
    float var = ws[WS_SUMSQ + c] / n - mu*mu;
    float sc = gamma[c] * rsqrtf(var + EPS_);
    ws[WS_SCALE + c] = sc;
    ws[WS_SHIFT + c] = beta[c] - mu * sc;
  }
}

// ---- K3: per-(b,c,r) spatial mean/max of y + fused crop-copy to out ----
__global__ void k_sstats(const float* __restrict__ x, float* __restrict__ ws,
                         float* __restrict__ out) {
  int r = blockIdx.x, c = blockIdx.y, b = blockIdx.z;
  int tid = threadIdx.x;
  float sc = ws[WS_SCALE + c], sh = ws[WS_SHIFT + c];
  const float* xp = x + (size_t)((b*C_ + c)*R_ + r) * HW_;
  const float4* p = (const float4*)xp;
  float s = 0.f, m = 0.f;
  for (int i = tid; i < HW_/4; i += 256) {
    float4 v = p[i];
    float a0 = fmaxf(fmaf(v.x, sc, sh), 0.f);
    float a1 = fmaxf(fmaf(v.y, sc, sh), 0.f);
    float a2 = fmaxf(fmaf(v.z, sc, sh), 0.f);
    float a3 = fmaxf(fmaf(v.w, sc, sh), 0.f);
    s += a0+a1+a2+a3; m = fmaxf(fmaxf(fmaxf(m, a0), fmaxf(a1, a2)), a3);
  }
  float* op = out + ((size_t)(b*OC_ + O_ + c)*R_ + r)*((size_t)HO_*WO_);
  for (int e = tid; e < HO_*WO_/4; e += 256) {
    int row = e >> 4, c4 = e & 15;
    const float* sp2 = xp + (row+1)*W_ + c4*4 + 1;
    float4 v = make_float4(sp2[0], sp2[1], sp2[2], sp2[3]);
    *(float4*)(op + row*WO_ + c4*4) = v;
  }
  __shared__ float rs[256], rm[256];
  rs[tid] = s; rm[tid] = m; __syncthreads();
  for (int off = 128; off > 0; off >>= 1) {
    if (tid < off) { rs[tid] += rs[tid+off]; rm[tid] = fmaxf(rm[tid], rm[tid+off]); }
    __syncthreads();
  }
  if (tid == 0) {
    int idx = (b*C_ + c)*R_ + r;
    ws[WS_SAVG + idx] = rs[0] / (float)HW_;
    ws[WS_SMAX + idx] = rm[0];
  }
}

// ---- K4: channel-pooled maps u_mean/u_max ----
__global__ void k_upool(const float* __restrict__ x, float* __restrict__ ws) {
  int r = blockIdx.y, b = blockIdx.z;
  int pos = blockIdx.x*256 + threadIdx.x;
  if (pos >= HW_) return;
  float s = 0.f, m = 0.f;
  for (int c = 0; c < C_; ++c) {
    float v = fmaxf(fmaf(x[(size_t)((b*C_ + c)*R_ + r)*HW_ + pos],
                         ws[WS_SCALE+c], ws[WS_SHIFT+c]), 0.f);
    s += v; m = fmaxf(m, v);
  }
  int idx = (b*R_ + r)*HW_ + pos;
  ws[WS_UMEAN + idx] = s / (float)C_;
  ws[WS_UMAX + idx] = m;
}

// ---- K5: channel attention MLP ----
__global__ void k_chatt(const float* __restrict__ fc1, const float* __restrict__ fc2,
                        float* __restrict__ ws) {
  int b = blockIdx.x, tid = threadIdx.x;
  __shared__ float sA[C_*R_], sM[C_*R_], hs[8];
  for (int i = tid; i < C_*R_; i += 256) {
    sA[i] = ws[WS_SAVG + b*C_*R_ + i];
    sM[i] = ws[WS_SMAX + b*C_*R_ + i];
  }
  __syncthreads();
  if (tid < 8) {
    int h = tid >> 1, e = tid & 1;
    float aA = 0.f, aM = 0.f;
    for (int c = 0; c < C_; ++c)
      for (int r = 0; r < R_; ++r) {
        float w = fc1[(e*C_ + c)*R_ + ((r - h) & 3)];
        aA += sA[c*R_ + r] * w;
        aM += sM[c*R_ + r] * w;
      }
    hs[tid] = fmaxf(aA, 0.f) + fmaxf(aM, 0.f);
  }
  __syncthreads();
  for (int idx = tid; idx < R_*C_*R_; idx += 256) {
    int h = idx / (C_*R_);
    int c = (idx % (C_*R_)) / R_;
    int r = idx & 3;
    int rr = (r - h) & 3;
    float v = hs[h*2+0] * fc2[(c*2+0)*R_ + rr]
            + hs[h*2+1] * fc2[(c*2+1)*R_ + rr];
    ws[WS_CHATT + b*R_*C_*R_ + idx] = sigm(v);
  }
}

// ---- K6: spatial attention 7x7 group conv ----
__global__ void k_spatt(const float* __restrict__ saw, float* __restrict__ ws) {
  int h = blockIdx.y, b = blockIdx.z;
  int tid = threadIdx.x;
  __shared__ float wl[2*R_*49];
  for (int e = tid; e < 2*R_*49; e += 256) {
    int g = e / (R_*49);
    int s = (e / 49) % R_;
    int ij = e % 49;
    int i = ij / 7, j = ij % 7;
    int si, sj;
    if (h == 0)      { si = i;     sj = j;     }
    else if (h == 1) { si = j;     sj = 6 - i; }
    else if (h == 2) { si = 6 - i; sj = 6 - j; }
    else             { si = 6 - j; sj = i;     }
    int srot = (s - h) & 3;
    wl[e] = saw[(g*R_ + srot)*49 + si*7 + sj];
  }
  __syncthreads();
  int pos = blockIdx.x*256 + tid;
  if (pos >= HW_) return;
  int y = pos / W_, xx = pos % W_;
  float acc = 0.f;
  for (int g = 0; g < 2; ++g) {
    const float* u = ws + (g ? WS_UMAX : WS_UMEAN) + (size_t)b*R_*HW_;
    for (int s = 0; s < R_; ++s) {
      const float* up = u + s*HW_;
      const float* wp = wl + (g*R_ + s)*49;
      for (int i = 0; i < 7; ++i) {
        int yy = y + i - 3;
        if (yy < 0 || yy >= H_) continue;
        for (int j = 0; j < 7; ++j) {
          int xc = xx + j - 3;
          if (xc < 0 || xc >= W_) continue;
          acc += up[yy*W_ + xc] * wp[i*7 + j];
        }
      }
    }
  }
  ws[WS_SPATT + (b*R_ + h)*HW_ + pos] = sigm(acc);
}

// ---- K7: pre-rotate conv weights into lane-ordered MFMA fragment images ----
__global__ void k_wrot(const float* __restrict__ cw, float* __restrict__ ws) {
  int chunk = blockIdx.x, h = blockIdx.y;
  __bf16* wp = (__bf16*)(ws + WS_WROT) + (size_t)(h*NCH_ + chunk)*WIMG_;
  for (int e = threadIdx.x; e < WIMG_; e += 256) {
    int kk = e & 7;
    int lane = (e >> 3) & 63;
    int nt = (e >> 9) % 3;
    int tap = e / (3*512);
    int o = nt*16 + (lane & 15);
    int plane = chunk*KP_ + (lane >> 4)*8 + kk;
    int c = plane >> 2, r = plane & 3;
    int rr = (r - h) & 3;
    int i = tap / 3, j = tap % 3;
    int si, sj;
    if (h == 0)      { si = i;     sj = j;     }
    else if (h == 1) { si = j;     sj = 2 - i; }
    else if (h == 2) { si = 2 - i; sj = 2 - j; }
    else             { si = 2 - j; sj = i;     }
    wp[e] = (__bf16)cw[((size_t)(o*C_ + c)*R_ + rr)*9 + si*3 + sj];
  }
}

// ---- K7b: z-pack producer — z[b][h][pg][pos][8] = relu(BN(x)) * ch_att * sp_att ----
// Written in the exact LDS fragment layout so k_conv2 staging is pure DMA.
__global__ void k_zpack(const float* __restrict__ x, float* __restrict__ ws) {
  int pg = blockIdx.y, b = blockIdx.z;
  int pos = blockIdx.x*256 + threadIdx.x;
  if (pos >= HW_) return;
  int c0 = pg*2;
  float sc0 = ws[WS_SCALE+c0],   sh0 = ws[WS_SHIFT+c0];
  float sc1 = ws[WS_SCALE+c0+1], sh1 = ws[WS_SHIFT+c0+1];
  const float* xp = x + (size_t)(b*C_ + c0)*R_*HW_ + pos;
  float yv[8];
  #pragma unroll
  for (int kk = 0; kk < 8; ++kk)
    yv[kk] = fmaxf(fmaf(xp[(size_t)kk*HW_], (kk < 4 ? sc0 : sc1),
                        (kk < 4 ? sh0 : sh1)), 0.f);
  __bf16* zp = (__bf16*)(ws + WS_Z);
  #pragma unroll
  for (int h = 0; h < R_; ++h) {
    float sa = ws[WS_SPATT + (size_t)(b*R_ + h)*HW_ + pos];
    const float* ca = ws + WS_CHATT + (size_t)(b*R_ + h)*C_*R_ + pg*8;
    bf16x8 pk;
    #pragma unroll
    for (int kk = 0; kk < 8; ++kk)
      pk[kk] = (__bf16)(yv[kk] * ca[kk] * sa);
    *(bf16x8*)&zp[(((size_t)(b*R_ + h)*NPG_ + pg)*HW_ + pos)*8] = pk;
  }
}

// ---- K8 (fallback path): main conv via MFMA implicit GEMM, fused transform ----
__global__ __launch_bounds__(512, 2) void k_conv(
    const float* __restrict__ x, const float* __restrict__ ws,
    float* __restrict__ out) {
  int ytile = blockIdx.x, h = blockIdx.y, b = blockIdx.z;
  int y0 = ytile * ROWS_;
  int tid = threadIdx.x;
  int lane = tid & 63, wave = tid >> 6;
  int m = lane & 15, quad = lane >> 4;
  int colgrp = wave & 1, rowgrp = wave >> 1;
  int dy0 = rowgrp * 4, colbase = colgrp * 32;

  __shared__ __align__(16) __bf16 zl[4*GPC_*8];
  __shared__ __align__(16) __bf16 wl[WIMG_];
  __shared__ float satt_l[GPC_];
  __shared__ float catt_l[C_*R_];
  __shared__ float scl[C_], shl[C_];

  const float* sp = ws + WS_SPATT + (size_t)(b*R_ + h)*HW_;
  for (int e = tid; e < GPC_; e += 512) satt_l[e] = sp[(y0 + e/W_)*W_ + e%W_];
  const float* chatt = ws + WS_CHATT + (size_t)(b*R_ + h)*C_*R_;
  for (int e = tid; e < C_*R_; e += 512) catt_l[e] = chatt[e];
  for (int e = tid; e < C_; e += 512) { scl[e] = ws[WS_SCALE+e]; shl[e] = ws[WS_SHIFT+e]; }

  f32x4 acc[4][2][3];
  #pragma unroll
  for (int dy = 0; dy < 4; ++dy)
    #pragma unroll
    for (int gi = 0; gi < 2; ++gi)
      #pragma unroll
      for (int nt = 0; nt < 3; ++nt) acc[dy][gi][nt] = (f32x4){0.f,0.f,0.f,0.f};

  const __bf16* wglob = (const __bf16*)(ws + WS_WROT) + (size_t)h*NCH_*WIMG_;
  int sq = tid & 3, sg0 = tid >> 2;
  __syncthreads();

  for (int chunk = 0; chunk < NCH_; ++chunk) {
    int pbase = chunk*KP_ + sq*8;
    int cb = pbase >> 2;
    float sc0 = scl[cb], sh0 = shl[cb], sc1 = scl[cb+1], sh1 = shl[cb+1];
    float ca[8];
    #pragma unroll
    for (int kk = 0; kk < 8; ++kk) ca[kk] = catt_l[pbase + kk];

    for (int g = sg0; g < GPC_; g += 128) {
      int row = g / W_, col = g - row*W_;
      const float* xp = x + (size_t)(b*C_*R_ + pbase)*HW_ + (y0+row)*W_ + col;
      float sa = satt_l[g];
      bf16x8 pk;
      #pragma unroll
      for (int kk = 0; kk < 8; ++kk) {
        float yv = fmaxf(fmaf(xp[kk*HW_], (kk < 4 ? sc0 : sc1),
                              (kk < 4 ? sh0 : sh1)), 0.f);
        pk[kk] = (__bf16)(yv * ca[kk] * sa);
      }
      *(bf16x8*)&zl[(sq*GPC_ + g)*8] = pk;
    }
    {
      const uint4* wsrc = (const uint4*)(wglob + (size_t)chunk*WIMG_);
      uint4* wdst = (uint4*)wl;
      for (int e = tid; e < WIMG_/8; e += 512) wdst[e] = wsrc[e];
    }
    __syncthreads();
    #pragma unroll
    for (int j = 0; j < 3; ++j) {
      bf16x8 zf[6][2];
      #pragma unroll
      for (int rr = 0; rr < 6; ++rr)
        #pragma unroll
        for (int gi = 0; gi < 2; ++gi)
          zf[rr][gi] = *(const bf16x8*)
              &zl[(quad*GPC_ + (dy0+rr)*W_ + colbase + gi*16 + m + j)*8];
      #pragma unroll
      for (int i = 0; i < 3; ++i) {
        int tap = i*3 + j;
        bf16x8 wf[3];
        #pragma unroll
        for (int nt = 0; nt < 3; ++nt)
          wf[nt] = *(const bf16x8*)&wl[((tap*3 + nt)*64 + lane)*8];
        #pragma unroll
        for (int dy = 0; dy < 4; ++dy)
          #pragma unroll
          for (int gi = 0; gi < 2; ++gi)
            #pragma unroll
            for (int nt = 0; nt < 3; ++nt)
              acc[dy][gi][nt] = __builtin_amdgcn_mfma_f32_16x16x32_bf16(
                  wf[nt], zf[dy+i][gi], acc[dy][gi][nt], 0, 0, 0);
      }
    }
    __syncthreads();
  }
  #pragma unroll
  for (int dy = 0; dy < 4; ++dy)
    #pragma unroll
    for (int gi = 0; gi < 2; ++gi)
      #pragma unroll
      for (int nt = 0; nt < 3; ++nt) {
        int col = colbase + gi*16 + m;
        #pragma unroll
        for (int e = 0; e < 4; ++e) {
          int o = nt*16 + quad*4 + e;
          out[((size_t)(b*OC_ + o)*R_ + h)*((size_t)HO_*WO_)
              + (y0 + dy0 + dy)*WO_ + col] = acc[dy][gi][nt][e];
        }
      }
}

// ---- K8b: main conv, pure-DMA staging, 8-row tile -> 69.9 KB LDS, 2 blocks/CU ----
// 8 waves = 2 rowgroups x 4 colgroups; wave tile 4 dy x 16 cols x 48 O.
__global__ __launch_bounds__(512, 4) void k_conv2(
    const float* __restrict__ ws, float* __restrict__ out) {
  int ytile = blockIdx.x, h = blockIdx.y, b = blockIdx.z;
  int y0 = ytile * ROWS2_;
  int tid = threadIdx.x;
  int lane = tid & 63, wave = tid >> 6;
  int m = lane & 15, quad = lane >> 4;
  int colgrp = wave & 3, rowgrp = wave >> 2;
  int dy0 = rowgrp * 4, colbase = colgrp * 16;

  __shared__ __align__(16) __bf16 zl[4*GPC2_*8];  // 42240 B
  __shared__ __align__(16) __bf16 wl[WIMG_];      // 27648 B

  f32x4 acc[4][3];
  #pragma unroll
  for (int dy = 0; dy < 4; ++dy)
    #pragma unroll
    for (int nt = 0; nt < 3; ++nt) acc[dy][nt] = (f32x4){0.f,0.f,0.f,0.f};

  const __bf16* wglob = (const __bf16*)(ws + WS_WROT) + (size_t)h*NCH_*WIMG_;
  const __bf16* zglob = (const __bf16*)(ws + WS_Z)
      + (size_t)(b*R_ + h)*NPG_*HW_*8 + (size_t)y0*W_*8;

  for (int chunk = 0; chunk < NCH_; ++chunk) {
    // stage z: 4 contiguous spans (one per 8-plane quad), linear LDS dest
    const __bf16* zb = zglob + (size_t)(chunk*4)*HW_*8;
    for (int e = tid; e < 4*GPC2_; e += 512) {
      int sq = e / GPC2_, off = e - sq*GPC2_;
      gl_lds16(zb + ((size_t)sq*HW_ + off)*8, &zl[e*8]);
    }
    // stage weights: straight DMA of lane-ordered image
    const __bf16* wsrc = wglob + (size_t)chunk*WIMG_;
    for (int e = tid; e < WIMG_/8; e += 512)
      gl_lds16(wsrc + (size_t)e*8, &wl[e*8]);
    __syncthreads();   // drains vmcnt(0): all DMA landed
    #pragma unroll
    for (int j = 0; j < 3; ++j) {
      bf16x8 zf[6];
      #pragma unroll
      for (int rr = 0; rr < 6; ++rr)
        zf[rr] = *(const bf16x8*)
            &zl[(quad*GPC2_ + (dy0+rr)*W_ + colbase + m + j)*8];
      #pragma unroll
      for (int i = 0; i < 3; ++i) {
        int tap = i*3 + j;
        bf16x8 wf[3];
        #pragma unroll
        for (int nt = 0; nt < 3; ++nt)
          wf[nt] = *(const bf16x8*)&wl[((tap*3 + nt)*64 + lane)*8];
        #pragma unroll
        for (int dy = 0; dy < 4; ++dy)
          #pragma unroll
          for (int nt = 0; nt < 3; ++nt)
            acc[dy][nt] = __builtin_amdgcn_mfma_f32_16x16x32_bf16(
                wf[nt], zf[dy+i], acc[dy][nt], 0, 0, 0);
      }
    }
    __syncthreads();   // all reads done before next chunk's DMA overwrites
  }
  // epilogue: D layout col(n=spatial)=lane&15, row(m=o_local)=quad*4+e
  #pragma unroll
  for (int dy = 0; dy < 4; ++dy)
    #pragma unroll
    for (int nt = 0; nt < 3; ++nt) {
      int col = colbase + m;
      #pragma unroll
      for (int e = 0; e < 4; ++e) {
        int o = nt*16 + quad*4 + e;
        out[((size_t)(b*OC_ + o)*R_ + h)*((size_t)HO_*WO_)
            + (y0 + dy0 + dy)*WO_ + col] = acc[dy][nt][e];
      }
    }
}

extern "C" void kernel_launch(void* const* d_in, const int* in_sizes, int n_in,
                              void* d_out, int out_size, void* d_ws, size_t ws_size,
                              hipStream_t stream) {
  const float* x     = (const float*)d_in[0];
  const float* gamma = (const float*)d_in[1];
  const float* beta  = (const float*)d_in[2];
  const float* fc1   = (const float*)d_in[3];
  const float* fc2   = (const float*)d_in[4];
  const float* saw   = (const float*)d_in[5];
  const float* cw    = (const float*)d_in[6];
  float* out = (float*)d_out;
  float* ws = (float*)d_ws;

  hipMemsetAsync(d_ws, 0, WS_SCALE * sizeof(float), stream);
  k_bn_stats   <<<dim3(B_, C_),                256, 0, stream>>>(x, ws);
  k_bn_finalize<<<1, 128,                           0, stream>>>(gamma, beta, ws);
  k_wrot       <<<dim3(NCH_, R_),              256, 0, stream>>>(cw, ws);
  k_sstats     <<<dim3(R_, C_, B_),            256, 0, stream>>>(x, ws, out);
  k_upool      <<<dim3((HW_+255)/256, R_, B_), 256, 0, stream>>>(x, ws);
  k_chatt      <<<B_, 256,                          0, stream>>>(fc1, fc2, ws);
  k_spatt      <<<dim3((HW_+255)/256, R_, B_), 256, 0, stream>>>(saw, ws);

  if ((unsigned long long)ws_size >= WS_NEED_BYTES) {
    // fast path: pre-pack attention-gated z, then pure-DMA MFMA conv (2 blk/CU)
    k_zpack<<<dim3((HW_+255)/256, NPG_, B_),   256, 0, stream>>>(x, ws);
    k_conv2<<<dim3(HO_/ROWS2_, R_, B_),        512, 0, stream>>>(ws, out);
  } else {
    // fallback: verified fused-transform conv (workspace too small for z)
    k_conv <<<dim3(HO_/ROWS_, R_, B_),         512, 0, stream>>>(x, ws, out);
  }
}

// Round 5
// 450.738 us; speedup vs baseline: 1.6041x; 1.1620x over previous
//
#include <hip/hip_runtime.h>
#include <hip/hip_bf16.h>
#include <math.h>

constexpr int B_ = 16, C_ = 96, O_ = 48, R_ = 4, H_ = 66, W_ = 66;
constexpr int HW_ = H_ * W_;            // 4356
constexpr int HO_ = 64, WO_ = 64;       // valid-conv output spatial
constexpr int OC_ = O_ + C_;            // 144 output channels
constexpr float EPS_ = 2e-5f;
constexpr int KP_ = 32;                 // planes per K-chunk
constexpr int NCH_ = (C_*R_)/KP_;       // 12 chunks
constexpr int NPG_ = (C_*R_)/8;         // 48 plane-groups (8 planes each)
constexpr int ROWS_ = 16;               // out-rows per block (fallback k_conv)
constexpr int SR_ = ROWS_ + 2;          // staged input rows (halo)
constexpr int GPC_ = SR_*W_;            // 1188 positions per quad-plane-group
constexpr int ROWS2_ = 8;               // out-rows per block (k_conv2: 2 blocks/CU)
constexpr int SR2_ = ROWS2_ + 2;        // 10
constexpr int GPC2_ = SR2_*W_;          // 660
constexpr int WIMG_ = 9*3*64*8;         // 13824 bf16 per (h,chunk) weight image

// workspace layout (float offsets)
constexpr int WS_SUM   = 0;
constexpr int WS_SUMSQ = WS_SUM + C_;
constexpr int WS_SCALE = WS_SUMSQ + C_;
constexpr int WS_SHIFT = WS_SCALE + C_;
constexpr int WS_SAVG  = WS_SHIFT + C_;                    // [B][C][R]
constexpr int WS_SMAX  = WS_SAVG + B_*C_*R_;
constexpr int WS_CHATT = WS_SMAX + B_*C_*R_;               // [B][h][C][r]
constexpr int WS_UMEAN = WS_CHATT + B_*R_*C_*R_;           // [B][r][HW]
constexpr int WS_UMAX  = WS_UMEAN + B_*R_*HW_;
constexpr int WS_SPATT = WS_UMAX + B_*R_*HW_;              // [B][h][HW]
constexpr int WS_WROT  = WS_SPATT + B_*R_*HW_;             // bf16 [h][chunk][tap][nt][lane][8]
constexpr int WS_Z     = WS_WROT + (R_*NCH_*WIMG_)/2;      // bf16 z[b][h][pg][pos][8]
constexpr long long Z_BF16 = (long long)B_*R_*NPG_*HW_*8;  // 107,053,056 elements
constexpr unsigned long long WS_NEED_BYTES =
    (unsigned long long)WS_Z*4ull + (unsigned long long)Z_BF16*2ull; // ~219 MB

typedef __attribute__((ext_vector_type(8))) __bf16 bf16x8;
typedef __attribute__((ext_vector_type(4))) float f32x4;

__device__ __forceinline__ float sigm(float v){ return 1.0f/(1.0f + __expf(-v)); }

// async global->LDS, 16B per lane; LDS dest must be linear (base + lane*16)
__device__ __forceinline__ void gl_lds16(const void* g, void* l) {
  __builtin_amdgcn_global_load_lds(
      (const __attribute__((address_space(1))) unsigned int*)g,
      (__attribute__((address_space(3))) unsigned int*)l, 16, 0, 0);
}

// ---- K1: BN batch statistics ----
__global__ void k_bn_stats(const float* __restrict__ x, float* __restrict__ ws) {
  int b = blockIdx.x, c = blockIdx.y;
  const float4* p = (const float4*)(x + (size_t)(b*C_ + c) * (R_*HW_));
  int tid = threadIdx.x;
  float s = 0.f, ss = 0.f;
  for (int i = tid; i < R_*HW_/4; i += 256) {
    float4 v = p[i];
    s += v.x + v.y + v.z + v.w;
    ss += v.x*v.x + v.y*v.y + v.z*v.z + v.w*v.w;
  }
  __shared__ float rs[256], rq[256];
  rs[tid] = s; rq[tid] = ss; __syncthreads();
  for (int off = 128; off > 0; off >>= 1) {
    if (tid < off) { rs[tid] += rs[tid+off]; rq[tid] += rq[tid+off]; }
    __syncthreads();
  }
  if (tid == 0) {
    atomicAdd(&ws[WS_SUM + c], rs[0]);
    atomicAdd(&ws[WS_SUMSQ + c], rq[0]);
  }
}

// ---- K2: finalize scale/shift ----
__global__ void k_bn_finalize(const float* __restrict__ gamma, const float* __restrict__ beta,
                              float* __restrict__ ws) {
  int c = threadIdx.x;
  if (c < C_) {
    float n = (float)(B_ * R_ * HW_);
    float mu = ws[WS_SUM + c] / n;
    float var = ws[WS_SUMSQ + c] / n - mu*mu;
    float sc = gamma[c] * rsqrtf(var + EPS_);
    ws[WS_SCALE + c] = sc;
    ws[WS_SHIFT + c] = beta[c] - mu * sc;
  }
}

// ---- K3: per-(b,c,r) spatial mean/max of y + fused crop-copy to out ----
__global__ void k_sstats(const float* __restrict__ x, float* __restrict__ ws,
                         float* __restrict__ out) {
  int r = blockIdx.x, c = blockIdx.y, b = blockIdx.z;
  int tid = threadIdx.x;
  float sc = ws[WS_SCALE + c], sh = ws[WS_SHIFT + c];
  const float* xp = x + (size_t)((b*C_ + c)*R_ + r) * HW_;
  const float4* p = (const float4*)xp;
  float s = 0.f, m = 0.f;
  for (int i = tid; i < HW_/4; i += 256) {
    float4 v = p[i];
    float a0 = fmaxf(fmaf(v.x, sc, sh), 0.f);
    float a1 = fmaxf(fmaf(v.y, sc, sh), 0.f);
    float a2 = fmaxf(fmaf(v.z, sc, sh), 0.f);
    float a3 = fmaxf(fmaf(v.w, sc, sh), 0.f);
    s += a0+a1+a2+a3; m = fmaxf(fmaxf(fmaxf(m, a0), fmaxf(a1, a2)), a3);
  }
  float* op = out + ((size_t)(b*OC_ + O_ + c)*R_ + r)*((size_t)HO_*WO_);
  for (int e = tid; e < HO_*WO_/4; e += 256) {
    int row = e >> 4, c4 = e & 15;
    const float* sp2 = xp + (row+1)*W_ + c4*4 + 1;
    float4 v = make_float4(sp2[0], sp2[1], sp2[2], sp2[3]);
    *(float4*)(op + row*WO_ + c4*4) = v;
  }
  __shared__ float rs[256], rm[256];
  rs[tid] = s; rm[tid] = m; __syncthreads();
  for (int off = 128; off > 0; off >>= 1) {
    if (tid < off) { rs[tid] += rs[tid+off]; rm[tid] = fmaxf(rm[tid], rm[tid+off]); }
    __syncthreads();
  }
  if (tid == 0) {
    int idx = (b*C_ + c)*R_ + r;
    ws[WS_SAVG + idx] = rs[0] / (float)HW_;
    ws[WS_SMAX + idx] = rm[0];
  }
}

// ---- K4: channel-pooled maps u_mean/u_max ----
__global__ void k_upool(const float* __restrict__ x, float* __restrict__ ws) {
  int r = blockIdx.y, b = blockIdx.z;
  int pos = blockIdx.x*256 + threadIdx.x;
  if (pos >= HW_) return;
  float s = 0.f, m = 0.f;
  for (int c = 0; c < C_; ++c) {
    float v = fmaxf(fmaf(x[(size_t)((b*C_ + c)*R_ + r)*HW_ + pos],
                         ws[WS_SCALE+c], ws[WS_SHIFT+c]), 0.f);
    s += v; m = fmaxf(m, v);
  }
  int idx = (b*R_ + r)*HW_ + pos;
  ws[WS_UMEAN + idx] = s / (float)C_;
  ws[WS_UMAX + idx] = m;
}

// ---- K5: channel attention MLP ----
__global__ void k_chatt(const float* __restrict__ fc1, const float* __restrict__ fc2,
                        float* __restrict__ ws) {
  int b = blockIdx.x, tid = threadIdx.x;
  __shared__ float sA[C_*R_], sM[C_*R_], hs[8];
  for (int i = tid; i < C_*R_; i += 256) {
    sA[i] = ws[WS_SAVG + b*C_*R_ + i];
    sM[i] = ws[WS_SMAX + b*C_*R_ + i];
  }
  __syncthreads();
  if (tid < 8) {
    int h = tid >> 1, e = tid & 1;
    float aA = 0.f, aM = 0.f;
    for (int c = 0; c < C_; ++c)
      for (int r = 0; r < R_; ++r) {
        float w = fc1[(e*C_ + c)*R_ + ((r - h) & 3)];
        aA += sA[c*R_ + r] * w;
        aM += sM[c*R_ + r] * w;
      }
    hs[tid] = fmaxf(aA, 0.f) + fmaxf(aM, 0.f);
  }
  __syncthreads();
  for (int idx = tid; idx < R_*C_*R_; idx += 256) {
    int h = idx / (C_*R_);
    int c = (idx % (C_*R_)) / R_;
    int r = idx & 3;
    int rr = (r - h) & 3;
    float v = hs[h*2+0] * fc2[(c*2+0)*R_ + rr]
            + hs[h*2+1] * fc2[(c*2+1)*R_ + rr];
    ws[WS_CHATT + b*R_*C_*R_ + idx] = sigm(v);
  }
}

// ---- K6: spatial attention 7x7 group conv, all 4 h fused, LDS zero-padded ----
// Block: 4 out-rows x 66 cols for one b. LDS: u tile 8 maps x 10 rows x 72 cols
// (zero-padded -> no bounds checks) + float4 weights (all 4 h per tap).
__global__ void k_spatt(const float* __restrict__ saw, float* __restrict__ ws) {
  int b = blockIdx.y;
  int y0 = blockIdx.x * 4;
  int tid = threadIdx.x;
  __shared__ float su[8*10*72];          // 23040 B
  __shared__ float4 swl[2*4*49];         // 6272 B

  for (int idx = tid; idx < 8*10*72; idx += 256) {
    int map = idx / 720, rem = idx - map*720;
    int ry = rem / 72, rx = rem - ry*72;
    int gy = y0 - 3 + ry, gx = rx - 3;
    int g = map >> 2, s = map & 3;
    float v = 0.f;
    if (gy >= 0 && gy < H_ && gx >= 0 && gx < W_)
      v = ws[(g ? WS_UMAX : WS_UMEAN) + (size_t)(b*R_ + s)*HW_ + gy*W_ + gx];
    su[idx] = v;
  }
  for (int e = tid; e < 2*4*49; e += 256) {
    int g = e / (4*49);
    int s = (e / 49) & 3;
    int ij = e % 49, i = ij / 7, j = ij % 7;
    float4 w;
    w.x = saw[(g*R_ + ( s      & 3))*49 + i*7 + j];            // h=0
    w.y = saw[(g*R_ + ((s - 1) & 3))*49 + j*7 + (6 - i)];      // h=1
    w.z = saw[(g*R_ + ((s - 2) & 3))*49 + (6 - i)*7 + (6 - j)];// h=2
    w.w = saw[(g*R_ + ((s - 3) & 3))*49 + (6 - j)*7 + i];      // h=3
    swl[e] = w;
  }
  __syncthreads();
  for (int e = tid; e < 4*W_; e += 256) {
    int ly = e / W_, lx = e - ly*W_;
    int y = y0 + ly;
    float a0 = 0.f, a1 = 0.f, a2 = 0.f, a3 = 0.f;
    for (int map = 0; map < 8; ++map) {
      const float* sp = &su[map*720 + ly*72 + lx];
      const float4* wp = &swl[map*49];
      #pragma unroll
      for (int i = 0; i < 7; ++i)
        #pragma unroll
        for (int j = 0; j < 7; ++j) {
          float v = sp[i*72 + j];
          float4 w = wp[i*7 + j];
          a0 = fmaf(v, w.x, a0); a1 = fmaf(v, w.y, a1);
          a2 = fmaf(v, w.z, a2); a3 = fmaf(v, w.w, a3);
        }
    }
    if (y < H_) {
      size_t base = WS_SPATT + (size_t)b*R_*HW_ + y*W_ + lx;
      ws[base + 0*HW_] = sigm(a0);
      ws[base + 1*HW_] = sigm(a1);
      ws[base + 2*HW_] = sigm(a2);
      ws[base + 3*HW_] = sigm(a3);
    }
  }
}

// ---- K7: pre-rotate conv weights into lane-ordered MFMA fragment images ----
__global__ void k_wrot(const float* __restrict__ cw, float* __restrict__ ws) {
  int chunk = blockIdx.x, h = blockIdx.y;
  __bf16* wp = (__bf16*)(ws + WS_WROT) + (size_t)(h*NCH_ + chunk)*WIMG_;
  for (int e = threadIdx.x; e < WIMG_; e += 256) {
    int kk = e & 7;
    int lane = (e >> 3) & 63;
    int nt = (e >> 9) % 3;
    int tap = e / (3*512);
    int o = nt*16 + (lane & 15);
    int plane = chunk*KP_ + (lane >> 4)*8 + kk;
    int c = plane >> 2, r = plane & 3;
    int rr = (r - h) & 3;
    int i = tap / 3, j = tap % 3;
    int si, sj;
    if (h == 0)      { si = i;     sj = j;     }
    else if (h == 1) { si = j;     sj = 2 - i; }
    else if (h == 2) { si = 2 - i; sj = 2 - j; }
    else             { si = 2 - j; sj = i;     }
    wp[e] = (__bf16)cw[((size_t)(o*C_ + c)*R_ + rr)*9 + si*3 + sj];
  }
}

// ---- K7b: z-pack producer — z[b][h][pg][pos][8] = relu(BN(x)) * ch_att * sp_att ----
// Written in the exact LDS fragment layout so k_conv2 staging is pure DMA.
__global__ void k_zpack(const float* __restrict__ x, float* __restrict__ ws) {
  int pg = blockIdx.y, b = blockIdx.z;
  int pos = blockIdx.x*256 + threadIdx.x;
  if (pos >= HW_) return;
  int c0 = pg*2;
  float sc0 = ws[WS_SCALE+c0],   sh0 = ws[WS_SHIFT+c0];
  float sc1 = ws[WS_SCALE+c0+1], sh1 = ws[WS_SHIFT+c0+1];
  const float* xp = x + (size_t)(b*C_ + c0)*R_*HW_ + pos;
  float yv[8];
  #pragma unroll
  for (int kk = 0; kk < 8; ++kk)
    yv[kk] = fmaxf(fmaf(xp[(size_t)kk*HW_], (kk < 4 ? sc0 : sc1),
                        (kk < 4 ? sh0 : sh1)), 0.f);
  __bf16* zp = (__bf16*)(ws + WS_Z);
  #pragma unroll
  for (int h = 0; h < R_; ++h) {
    float sa = ws[WS_SPATT + (size_t)(b*R_ + h)*HW_ + pos];
    const float* ca = ws + WS_CHATT + (size_t)(b*R_ + h)*C_*R_ + pg*8;
    bf16x8 pk;
    #pragma unroll
    for (int kk = 0; kk < 8; ++kk)
      pk[kk] = (__bf16)(yv[kk] * ca[kk] * sa);
    *(bf16x8*)&zp[(((size_t)(b*R_ + h)*NPG_ + pg)*HW_ + pos)*8] = pk;
  }
}

// ---- K8 (fallback path): main conv via MFMA implicit GEMM, fused transform ----
__global__ __launch_bounds__(512, 2) void k_conv(
    const float* __restrict__ x, const float* __restrict__ ws,
    float* __restrict__ out) {
  int ytile = blockIdx.x, h = blockIdx.y, b = blockIdx.z;
  int y0 = ytile * ROWS_;
  int tid = threadIdx.x;
  int lane = tid & 63, wave = tid >> 6;
  int m = lane & 15, quad = lane >> 4;
  int colgrp = wave & 1, rowgrp = wave >> 1;
  int dy0 = rowgrp * 4, colbase = colgrp * 32;

  __shared__ __align__(16) __bf16 zl[4*GPC_*8];
  __shared__ __align__(16) __bf16 wl[WIMG_];
  __shared__ float satt_l[GPC_];
  __shared__ float catt_l[C_*R_];
  __shared__ float scl[C_], shl[C_];

  const float* sp = ws + WS_SPATT + (size_t)(b*R_ + h)*HW_;
  for (int e = tid; e < GPC_; e += 512) satt_l[e] = sp[(y0 + e/W_)*W_ + e%W_];
  const float* chatt = ws + WS_CHATT + (size_t)(b*R_ + h)*C_*R_;
  for (int e = tid; e < C_*R_; e += 512) catt_l[e] = chatt[e];
  for (int e = tid; e < C_; e += 512) { scl[e] = ws[WS_SCALE+e]; shl[e] = ws[WS_SHIFT+e]; }

  f32x4 acc[4][2][3];
  #pragma unroll
  for (int dy = 0; dy < 4; ++dy)
    #pragma unroll
    for (int gi = 0; gi < 2; ++gi)
      #pragma unroll
      for (int nt = 0; nt < 3; ++nt) acc[dy][gi][nt] = (f32x4){0.f,0.f,0.f,0.f};

  const __bf16* wglob = (const __bf16*)(ws + WS_WROT) + (size_t)h*NCH_*WIMG_;
  int sq = tid & 3, sg0 = tid >> 2;
  __syncthreads();

  for (int chunk = 0; chunk < NCH_; ++chunk) {
    int pbase = chunk*KP_ + sq*8;
    int cb = pbase >> 2;
    float sc0 = scl[cb], sh0 = shl[cb], sc1 = scl[cb+1], sh1 = shl[cb+1];
    float ca[8];
    #pragma unroll
    for (int kk = 0; kk < 8; ++kk) ca[kk] = catt_l[pbase + kk];

    for (int g = sg0; g < GPC_; g += 128) {
      int row = g / W_, col = g - row*W_;
      const float* xp = x + (size_t)(b*C_*R_ + pbase)*HW_ + (y0+row)*W_ + col;
      float sa = satt_l[g];
      bf16x8 pk;
      #pragma unroll
      for (int kk = 0; kk < 8; ++kk) {
        float yv = fmaxf(fmaf(xp[kk*HW_], (kk < 4 ? sc0 : sc1),
                              (kk < 4 ? sh0 : sh1)), 0.f);
        pk[kk] = (__bf16)(yv * ca[kk] * sa);
      }
      *(bf16x8*)&zl[(sq*GPC_ + g)*8] = pk;
    }
    {
      const uint4* wsrc = (const uint4*)(wglob + (size_t)chunk*WIMG_);
      uint4* wdst = (uint4*)wl;
      for (int e = tid; e < WIMG_/8; e += 512) wdst[e] = wsrc[e];
    }
    __syncthreads();
    #pragma unroll
    for (int j = 0; j < 3; ++j) {
      bf16x8 zf[6][2];
      #pragma unroll
      for (int rr = 0; rr < 6; ++rr)
        #pragma unroll
        for (int gi = 0; gi < 2; ++gi)
          zf[rr][gi] = *(const bf16x8*)
              &zl[(quad*GPC_ + (dy0+rr)*W_ + colbase + gi*16 + m + j)*8];
      #pragma unroll
      for (int i = 0; i < 3; ++i) {
        int tap = i*3 + j;
        bf16x8 wf[3];
        #pragma unroll
        for (int nt = 0; nt < 3; ++nt)
          wf[nt] = *(const bf16x8*)&wl[((tap*3 + nt)*64 + lane)*8];
        #pragma unroll
        for (int dy = 0; dy < 4; ++dy)
          #pragma unroll
          for (int gi = 0; gi < 2; ++gi)
            #pragma unroll
            for (int nt = 0; nt < 3; ++nt)
              acc[dy][gi][nt] = __builtin_amdgcn_mfma_f32_16x16x32_bf16(
                  wf[nt], zf[dy+i][gi], acc[dy][gi][nt], 0, 0, 0);
      }
    }
    __syncthreads();
  }
  #pragma unroll
  for (int dy = 0; dy < 4; ++dy)
    #pragma unroll
    for (int gi = 0; gi < 2; ++gi)
      #pragma unroll
      for (int nt = 0; nt < 3; ++nt) {
        int col = colbase + gi*16 + m;
        #pragma unroll
        for (int e = 0; e < 4; ++e) {
          int o = nt*16 + quad*4 + e;
          out[((size_t)(b*OC_ + o)*R_ + h)*((size_t)HO_*WO_)
              + (y0 + dy0 + dy)*WO_ + col] = acc[dy][gi][nt][e];
        }
      }
}

// ---- K8b: main conv, pure-DMA staging, 8-row tile -> 69.9 KB LDS, 2 blocks/CU ----
// 8 waves = 2 rowgroups x 4 colgroups; wave tile 4 dy x 16 cols x 48 O.
__global__ __launch_bounds__(512, 4) void k_conv2(
    const float* __restrict__ ws, float* __restrict__ out) {
  int ytile = blockIdx.x, h = blockIdx.y, b = blockIdx.z;
  int y0 = ytile * ROWS2_;
  int tid = threadIdx.x;
  int lane = tid & 63, wave = tid >> 6;
  int m = lane & 15, quad = lane >> 4;
  int colgrp = wave & 3, rowgrp = wave >> 2;
  int dy0 = rowgrp * 4, colbase = colgrp * 16;

  __shared__ __align__(16) __bf16 zl[4*GPC2_*8];  // 42240 B
  __shared__ __align__(16) __bf16 wl[WIMG_];      // 27648 B

  f32x4 acc[4][3];
  #pragma unroll
  for (int dy = 0; dy < 4; ++dy)
    #pragma unroll
    for (int nt = 0; nt < 3; ++nt) acc[dy][nt] = (f32x4){0.f,0.f,0.f,0.f};

  const __bf16* wglob = (const __bf16*)(ws + WS_WROT) + (size_t)h*NCH_*WIMG_;
  const __bf16* zglob = (const __bf16*)(ws + WS_Z)
      + (size_t)(b*R_ + h)*NPG_*HW_*8 + (size_t)y0*W_*8;

  for (int chunk = 0; chunk < NCH_; ++chunk) {
    // stage z: 4 contiguous spans (one per 8-plane quad), linear LDS dest
    const __bf16* zb = zglob + (size_t)(chunk*4)*HW_*8;
    for (int e = tid; e < 4*GPC2_; e += 512) {
      int sq = e / GPC2_, off = e - sq*GPC2_;
      gl_lds16(zb + ((size_t)sq*HW_ + off)*8, &zl[e*8]);
    }
    // stage weights: straight DMA of lane-ordered image
    const __bf16* wsrc = wglob + (size_t)chunk*WIMG_;
    for (int e = tid; e < WIMG_/8; e += 512)
      gl_lds16(wsrc + (size_t)e*8, &wl[e*8]);
    __syncthreads();   // drains vmcnt(0): all DMA landed
    #pragma unroll
    for (int j = 0; j < 3; ++j) {
      bf16x8 zf[6];
      #pragma unroll
      for (int rr = 0; rr < 6; ++rr)
        zf[rr] = *(const bf16x8*)
            &zl[(quad*GPC2_ + (dy0+rr)*W_ + colbase + m + j)*8];
      #pragma unroll
      for (int i = 0; i < 3; ++i) {
        int tap = i*3 + j;
        bf16x8 wf[3];
        #pragma unroll
        for (int nt = 0; nt < 3; ++nt)
          wf[nt] = *(const bf16x8*)&wl[((tap*3 + nt)*64 + lane)*8];
        #pragma unroll
        for (int dy = 0; dy < 4; ++dy)
          #pragma unroll
          for (int nt = 0; nt < 3; ++nt)
            acc[dy][nt] = __builtin_amdgcn_mfma_f32_16x16x32_bf16(
                wf[nt], zf[dy+i], acc[dy][nt], 0, 0, 0);
      }
    }
    __syncthreads();   // all reads done before next chunk's DMA overwrites
  }
  // epilogue: D layout col(n=spatial)=lane&15, row(m=o_local)=quad*4+e
  #pragma unroll
  for (int dy = 0; dy < 4; ++dy)
    #pragma unroll
    for (int nt = 0; nt < 3; ++nt) {
      int col = colbase + m;
      #pragma unroll
      for (int e = 0; e < 4; ++e) {
        int o = nt*16 + quad*4 + e;
        out[((size_t)(b*OC_ + o)*R_ + h)*((size_t)HO_*WO_)
            + (y0 + dy0 + dy)*WO_ + col] = acc[dy][nt][e];
      }
    }
}

extern "C" void kernel_launch(void* const* d_in, const int* in_sizes, int n_in,
                              void* d_out, int out_size, void* d_ws, size_t ws_size,
                              hipStream_t stream) {
  const float* x     = (const float*)d_in[0];
  const float* gamma = (const float*)d_in[1];
  const float* beta  = (const float*)d_in[2];
  const float* fc1   = (const float*)d_in[3];
  const float* fc2   = (const float*)d_in[4];
  const float* saw   = (const float*)d_in[5];
  const float* cw    = (const float*)d_in[6];
  float* out = (float*)d_out;
  float* ws = (float*)d_ws;

  hipMemsetAsync(d_ws, 0, WS_SCALE * sizeof(float), stream);
  k_bn_stats   <<<dim3(B_, C_),                256, 0, stream>>>(x, ws);
  k_bn_finalize<<<1, 128,                           0, stream>>>(gamma, beta, ws);
  k_wrot       <<<dim3(NCH_, R_),              256, 0, stream>>>(cw, ws);
  k_sstats     <<<dim3(R_, C_, B_),            256, 0, stream>>>(x, ws, out);
  k_upool      <<<dim3((HW_+255)/256, R_, B_), 256, 0, stream>>>(x, ws);
  k_chatt      <<<B_, 256,                          0, stream>>>(fc1, fc2, ws);
  k_spatt      <<<dim3((H_+3)/4, B_),          256, 0, stream>>>(saw, ws);

  if ((unsigned long long)ws_size >= WS_NEED_BYTES) {
    // fast path: pre-pack attention-gated z, then pure-DMA MFMA conv (2 blk/CU)
    k_zpack<<<dim3((HW_+255)/256, NPG_, B_),   256, 0, stream>>>(x, ws);
    k_conv2<<<dim3(HO_/ROWS2_, R_, B_),        512, 0, stream>>>(ws, out);
  } else {
    // fallback: verified fused-transform conv (workspace too small for z)
    k_conv <<<dim3(HO_/ROWS_, R_, B_),         512, 0, stream>>>(x, ws, out);
  }
}